// Round 1
// baseline (393.205 us; speedup 1.0000x reference)
//
#include <hip/hip_runtime.h>

typedef unsigned short u16;
typedef __attribute__((ext_vector_type(8))) short s16x8;   // 8 bf16 (4 VGPRs)
typedef __attribute__((ext_vector_type(4))) float f32x4;   // MFMA 16x16 accumulator

#define MFMA(a, b, c) __builtin_amdgcn_mfma_f32_16x16x32_bf16((a), (b), (c), 0, 0, 0)

// async global->LDS, 16B per lane; LDS dest must be wave-uniform base + lane*16
#define LDS16(gp, lp)                                                          \
  __builtin_amdgcn_global_load_lds(                                            \
      (__attribute__((address_space(1))) void*)(gp),                           \
      (__attribute__((address_space(3))) void*)(lp), 16, 0, 0)

__device__ __forceinline__ u16 f2bf(float f) {
  unsigned u = __float_as_uint(f);
  u += 0x7fffu + ((u >> 16) & 1u);   // round-to-nearest-even
  return (u16)(u >> 16);
}

// ---------------------------------------------------------------- cast x -> bf16
__global__ void cast_x_kernel(const float* __restrict__ in, u16* __restrict__ out) {
  const int idx = (blockIdx.x * 256 + threadIdx.x) * 4;
  const float4 v = *(const float4*)(in + idx);
  ushort4 o;
  o.x = f2bf(v.x); o.y = f2bf(v.y); o.z = f2bf(v.z); o.w = f2bf(v.w);
  *(ushort4*)(out + idx) = o;
}

// ------------------------------------------- transpose+cast: [Kd][Nd] f32 -> [Nd][Kd] bf16
__global__ void transpose_cast(const float* __restrict__ in, u16* __restrict__ out,
                               int Kd, int Nd) {
  __shared__ float t[64][65];
  const int tid = threadIdx.x;
  const int nb = blockIdx.x * 64, kb = blockIdx.y * 64;
#pragma unroll
  for (int it = 0; it < 4; it++) {
    const int flat = it * 1024 + tid * 4;
    const int rr = flat >> 6, cc = flat & 63;
    const float4 v = *(const float4*)(in + (size_t)(kb + rr) * Nd + nb + cc);
    t[rr][cc] = v.x; t[rr][cc + 1] = v.y; t[rr][cc + 2] = v.z; t[rr][cc + 3] = v.w;
  }
  __syncthreads();
#pragma unroll
  for (int it = 0; it < 4; it++) {
    const int flat = it * 1024 + tid * 4;
    const int rn = flat >> 6, ck = flat & 63;
    ushort4 o;
    o.x = f2bf(t[ck][rn]);     o.y = f2bf(t[ck + 1][rn]);
    o.z = f2bf(t[ck + 2][rn]); o.w = f2bf(t[ck + 3][rn]);
    *(ushort4*)(out + (size_t)(nb + rn) * Kd + kb + ck) = o;
  }
}

// ---------------------------------------------------------------- 128x128 bf16 GEMM
// C = A[M][1024] * Bt[N][1024]^T.  EPI=0: scatter qkv (bf16). EPI=1: fp32 C out.
template <int EPI>
__global__ __launch_bounds__(256, 2)
void gemm128(const u16* __restrict__ A, const u16* __restrict__ Bt,
             float* __restrict__ Cout, int Ndim,
             u16* __restrict__ qp, u16* __restrict__ kp, u16* __restrict__ vp) {
  __shared__ alignas(16) u16 As[128 * 32];
  __shared__ alignas(16) u16 Bs[128 * 32];
  const int tid = threadIdx.x;
  const int wave = tid >> 6, lane = tid & 63;
  const int r = lane & 15, qq = lane >> 4;
  const int wm = (wave >> 1) * 64, wn = (wave & 1) * 64;
  const int tn = blockIdx.x * 128, tm = blockIdx.y * 128;

  f32x4 acc[4][4];
#pragma unroll
  for (int i = 0; i < 4; i++)
#pragma unroll
    for (int j = 0; j < 4; j++) acc[i][j] = (f32x4){0.f, 0.f, 0.f, 0.f};

  const int c0 = tid, c1 = tid + 256;  // 16B chunks: row = c>>2, kchunk = c&3
  const u16* ga0 = A + (size_t)(tm + (c0 >> 2)) * 1024 + (c0 & 3) * 8;
  const u16* ga1 = A + (size_t)(tm + (c1 >> 2)) * 1024 + (c1 & 3) * 8;
  const u16* gb0 = Bt + (size_t)(tn + (c0 >> 2)) * 1024 + (c0 & 3) * 8;
  const u16* gb1 = Bt + (size_t)(tn + (c1 >> 2)) * 1024 + (c1 & 3) * 8;
  u16* la0 = As + c0 * 8; u16* la1 = As + c1 * 8;
  u16* lb0 = Bs + c0 * 8; u16* lb1 = Bs + c1 * 8;

  for (int k0 = 0; k0 < 1024; k0 += 32) {
    LDS16(ga0 + k0, la0);
    LDS16(ga1 + k0, la1);
    LDS16(gb0 + k0, lb0);
    LDS16(gb1 + k0, lb1);
    __syncthreads();
    s16x8 af[4], bfr[4];
#pragma unroll
    for (int f = 0; f < 4; f++)
      af[f] = *(const s16x8*)(As + (wm + f * 16 + r) * 32 + qq * 8);
#pragma unroll
    for (int f = 0; f < 4; f++)
      bfr[f] = *(const s16x8*)(Bs + (wn + f * 16 + r) * 32 + qq * 8);
#pragma unroll
    for (int fm = 0; fm < 4; fm++)
#pragma unroll
      for (int fn = 0; fn < 4; fn++)
        acc[fm][fn] = MFMA(af[fm], bfr[fn], acc[fm][fn]);
    __syncthreads();
  }

  // epilogue: C/D layout col = lane&15, row = (lane>>4)*4 + j2
  if (EPI == 0) {
#pragma unroll
    for (int fm = 0; fm < 4; fm++) {
#pragma unroll
      for (int j2 = 0; j2 < 4; j2++) {
        const int mm = tm + wm + fm * 16 + qq * 4 + j2;
        const int bb = mm >> 11, tt = mm & 2047;
#pragma unroll
        for (int fn = 0; fn < 4; fn++) {
          const int n = tn + wn + fn * 16 + r;
          const u16 bv = f2bf(acc[fm][fn][j2]);
          const int which = n >> 10;
          const int hh = (n >> 6) & 15, dd = n & 63;
          const int bhh = bb * 16 + hh;
          if (which == 0)      qp[((size_t)bhh * 2048 + tt) * 64 + dd] = bv;
          else if (which == 1) kp[((size_t)bhh * 2048 + tt) * 64 + dd] = bv;
          else                 vp[((size_t)bhh * 64 + dd) * 2048 + tt] = bv;  // V transposed
        }
      }
    }
  } else {
#pragma unroll
    for (int fm = 0; fm < 4; fm++) {
#pragma unroll
      for (int j2 = 0; j2 < 4; j2++) {
        const int mm = tm + wm + fm * 16 + qq * 4 + j2;
#pragma unroll
        for (int fn = 0; fn < 4; fn++) {
          const int n = tn + wn + fn * 16 + r;
          Cout[(size_t)mm * Ndim + n] = acc[fm][fn][j2];
        }
      }
    }
  }
}

// ---------------------------------------------------------------- flash attention
// Q,K in [BH][2048][64] bf16, V in [BH][64][2048] bf16 (pre-transposed).
// Swapped QK^T: S^T = mfma(K, Q) so each lane's softmax stats are for q = lane&15.
__global__ __launch_bounds__(256, 2)
void attn64(const u16* __restrict__ qg, const u16* __restrict__ kg,
            const u16* __restrict__ vtg, u16* __restrict__ yg) {
  __shared__ alignas(16) u16 Klds[32 * 64];  // [key][d], XOR-swizzled chunks
  __shared__ alignas(16) u16 Vlds[64 * 32];  // [d][key], pair-row XOR-swizzled
  const int tid = threadIdx.x;
  const int wave = tid >> 6, lane = tid & 63;
  const int r = lane & 15, qq = lane >> 4;
  const int qb = blockIdx.x * 64;
  const int bh = blockIdx.y;               // b*16 + h
  const int qrow = qb + wave * 16 + r;     // this lane's q (S^T column)

  const u16* qbase = qg + ((size_t)bh * 2048 + qrow) * 64;
  const s16x8 qf0 = *(const s16x8*)(qbase + qq * 8);
  const s16x8 qf1 = *(const s16x8*)(qbase + 32 + qq * 8);

  float m_run = -1e30f, l_run = 0.f;
  f32x4 yacc[4];
#pragma unroll
  for (int nt = 0; nt < 4; nt++) yacc[nt] = (f32x4){0.f, 0.f, 0.f, 0.f};

  // staging: thread i owns one 16B chunk of K-tile and one of V-tile
  const int i = tid;
  const int krow = i >> 3;
  const int kch = (i & 7) ^ (krow & 7);           // inverse swizzle on global side
  const u16* kgsrc = kg + ((size_t)bh * 2048 + krow) * 64 + kch * 8;
  const int vg = i >> 3;
  const int vch = (i & 7) ^ (vg & 7);
  const int vd = vg * 2 + (vch >> 2);
  const u16* vgsrc = vtg + ((size_t)bh * 64 + vd) * 2048 + (vch & 3) * 8;

  const int kvend = qb + 64;
  for (int kv0 = 0; kv0 < kvend; kv0 += 32) {
    LDS16(kgsrc + (size_t)kv0 * 64, Klds + i * 8);
    LDS16(vgsrc + kv0, Vlds + i * 8);
    __syncthreads();

    // S^T: rows = keys (two 16-sub-tiles), cols = q
    f32x4 sacc0 = {0.f, 0.f, 0.f, 0.f}, sacc1 = {0.f, 0.f, 0.f, 0.f};
    {
      const u16* kr0 = Klds + r * 64;          // key row r (kb=0)
      const int sw = r & 7;
      s16x8 k00 = *(const s16x8*)(kr0 + ((qq ^ sw) * 8));
      s16x8 k01 = *(const s16x8*)(kr0 + (((4 + qq) ^ sw) * 8));
      sacc0 = MFMA(k00, qf0, sacc0);
      sacc0 = MFMA(k01, qf1, sacc0);
      const u16* kr1 = Klds + (16 + r) * 64;   // key row 16+r (kb=1)
      s16x8 k10 = *(const s16x8*)(kr1 + ((qq ^ sw) * 8));
      s16x8 k11 = *(const s16x8*)(kr1 + (((4 + qq) ^ sw) * 8));
      sacc1 = MFMA(k10, qf0, sacc1);
      sacc1 = MFMA(k11, qf1, sacc1);
    }

    // scale + causal mask + online softmax (acc rows = keys: key = kv0+kb*16+qq*4+j)
    float p0[4], p1[4], mx = -1e30f;
#pragma unroll
    for (int j = 0; j < 4; j++) {
      const int key0 = kv0 + qq * 4 + j;
      const float s0 = (key0 <= qrow) ? sacc0[j] * 0.125f : -1e30f;
      const float s1 = (key0 + 16 <= qrow) ? sacc1[j] * 0.125f : -1e30f;
      p0[j] = s0; p1[j] = s1;
      mx = fmaxf(mx, fmaxf(s0, s1));
    }
    mx = fmaxf(mx, __shfl_xor(mx, 16));
    mx = fmaxf(mx, __shfl_xor(mx, 32));
    const float mnew = fmaxf(m_run, mx);
    float lsum = 0.f;
#pragma unroll
    for (int j = 0; j < 4; j++) {
      p0[j] = __expf(p0[j] - mnew);
      p1[j] = __expf(p1[j] - mnew);
      lsum += p0[j] + p1[j];
    }
    lsum += __shfl_xor(lsum, 16);
    lsum += __shfl_xor(lsum, 32);
    const float alpha = __expf(m_run - mnew);
    m_run = mnew;
    l_run = l_run * alpha + lsum;
#pragma unroll
    for (int j = 0; j < 4; j++) {  // rescale O rows (row q' = qq*4+j; stats live at lane q')
      const float fac = __shfl(alpha, qq * 4 + j);
      yacc[0][j] *= fac; yacc[1][j] *= fac; yacc[2][j] *= fac; yacc[3][j] *= fac;
    }

    // P (S^T layout: 8 keys @ fixed q per lane) -> PV A-frag (keys qq*8..qq*8+7) via shfl
    const int A0 = (int)((unsigned)f2bf(p0[0]) | ((unsigned)f2bf(p0[1]) << 16));
    const int B0 = (int)((unsigned)f2bf(p0[2]) | ((unsigned)f2bf(p0[3]) << 16));
    const int A1 = (int)((unsigned)f2bf(p1[0]) | ((unsigned)f2bf(p1[1]) << 16));
    const int B1 = (int)((unsigned)f2bf(p1[2]) | ((unsigned)f2bf(p1[3]) << 16));
    const int src0 = (qq & 1) * 32 + r;   // source quarter 2*(qq&1), same q column
    const int src1 = src0 + 16;
    const bool hi = ((qq >> 1) & 1) != 0; // dest quarters 2,3 take the kb=1 sub-tile
    const int w0a = __shfl(A0, src0), w0b = __shfl(A1, src0);
    const int w1a = __shfl(B0, src0), w1b = __shfl(B1, src0);
    const int w2a = __shfl(A0, src1), w2b = __shfl(A1, src1);
    const int w3a = __shfl(B0, src1), w3b = __shfl(B1, src1);
    int4 pw;
    pw.x = hi ? w0b : w0a;
    pw.y = hi ? w1b : w1a;
    pw.z = hi ? w2b : w2a;
    pw.w = hi ? w3b : w3a;
    union { int4 i4; s16x8 s8; } pu;
    pu.i4 = pw;

    // PV: B operand from V^T LDS (keys contiguous at fixed d)
#pragma unroll
    for (int nt = 0; nt < 4; nt++) {
      const int d = nt * 16 + r;
      const int g = d >> 1;
      const int ch = ((d & 1) * 4 + qq) ^ (g & 7);
      s16x8 vf = *(const s16x8*)(Vlds + g * 64 + ch * 8);
      yacc[nt] = MFMA(pu.s8, vf, yacc[nt]);
    }
    __syncthreads();
  }

  // finalize: divide by l, write y as [B][T][C] bf16
  const int b = bh >> 4, h = bh & 15;
#pragma unroll
  for (int j = 0; j < 4; j++) {
    const float linv = 1.0f / __shfl(l_run, qq * 4 + j);
    const int t = qb + wave * 16 + qq * 4 + j;
    u16* yrow = yg + ((size_t)b * 2048 + t) * 1024 + h * 64;
#pragma unroll
    for (int nt = 0; nt < 4; nt++)
      yrow[nt * 16 + r] = f2bf(yacc[nt][j] * linv);
  }
}

// ---------------------------------------------------------------- launcher
extern "C" void kernel_launch(void* const* d_in, const int* in_sizes, int n_in,
                              void* d_out, int out_size, void* d_ws, size_t ws_size,
                              hipStream_t stream) {
  const float* x = (const float*)d_in[0];       // [4,2048,1024]
  const float* wqkv = (const float*)d_in[1];    // [1024,3072]
  const float* wproj = (const float*)d_in[2];   // [1024,1024]
  float* out = (float*)d_out;                   // [4,2048,1024] fp32

  char* ws = (char*)d_ws;
  u16* xb     = (u16*)(ws);                 // 16.78 MB  [8192][1024] bf16
  u16* wqkvT  = (u16*)(ws + 16777216);      //  6.29 MB  [3072][1024] bf16
  u16* wprojT = (u16*)(ws + 23068672);      //  2.10 MB  [1024][1024] bf16
  u16* qw     = (u16*)(ws + 25165824);      // 16.78 MB  [64][2048][64]
  u16* kw     = (u16*)(ws + 41943040);      // 16.78 MB  [64][2048][64]
  u16* vtw    = (u16*)(ws + 58720256);      // 16.78 MB  [64][64][2048]
  u16* yw     = (u16*)(ws + 75497472);      // 16.78 MB  [8192][1024]
  (void)in_sizes; (void)n_in; (void)out_size; (void)ws_size;

  cast_x_kernel<<<8192, 256, 0, stream>>>(x, xb);
  transpose_cast<<<dim3(48, 16), 256, 0, stream>>>(wqkv, wqkvT, 1024, 3072);
  transpose_cast<<<dim3(16, 16), 256, 0, stream>>>(wproj, wprojT, 1024, 1024);
  gemm128<0><<<dim3(24, 64), 256, 0, stream>>>(xb, wqkvT, nullptr, 3072, qw, kw, vtw);
  attn64<<<dim3(32, 64), 256, 0, stream>>>(qw, kw, vtw, yw);
  gemm128<1><<<dim3(8, 64), 256, 0, stream>>>(yw, wprojT, out, 1024,
                                              nullptr, nullptr, nullptr);
}

// Round 3
// 317.254 us; speedup vs baseline: 1.2394x; 1.2394x over previous
//
#include <hip/hip_runtime.h>

typedef unsigned short u16;
typedef __attribute__((ext_vector_type(8))) short s16x8;   // 8 bf16 (4 VGPRs)
typedef __attribute__((ext_vector_type(4))) float f32x4;   // MFMA 16x16 accumulator
typedef __attribute__((ext_vector_type(16))) float f32x16; // MFMA 32x32 accumulator

#define MFMA(a, b, c) __builtin_amdgcn_mfma_f32_16x16x32_bf16((a), (b), (c), 0, 0, 0)
#define MFMA32(a, b, c) __builtin_amdgcn_mfma_f32_32x32x16_bf16((a), (b), (c), 0, 0, 0)

// async global->LDS, 16B per lane; LDS dest must be wave-uniform base + lane*16
#define LDS16(gp, lp)                                                          \
  __builtin_amdgcn_global_load_lds(                                            \
      (__attribute__((address_space(1))) void*)(gp),                           \
      (__attribute__((address_space(3))) void*)(lp), 16, 0, 0)

#if __has_builtin(__builtin_amdgcn_exp2f)
#define EXP2F(x) __builtin_amdgcn_exp2f(x)
#else
#define EXP2F(x) exp2f(x)
#endif
#if __has_builtin(__builtin_amdgcn_rcpf)
#define RCPF(x) __builtin_amdgcn_rcpf(x)
#else
#define RCPF(x) (1.0f / (x))
#endif

__device__ __forceinline__ u16 f2bf(float f) {
  unsigned u = __float_as_uint(f);
  u += 0x7fffu + ((u >> 16) & 1u);   // round-to-nearest-even
  return (u16)(u >> 16);
}

// pack two f32 -> 2x bf16 in one VGPR (lo = a, hi = b), RNE
__device__ __forceinline__ int cvtpk(float a, float b) {
  int r;
  asm("v_cvt_pk_bf16_f32 %0, %1, %2" : "=v"(r) : "v"(a), "v"(b));
  return r;
}

// ---------------------------------------------------------------- cast x -> bf16
__global__ void cast_x_kernel(const float* __restrict__ in, u16* __restrict__ out) {
  const int idx = (blockIdx.x * 256 + threadIdx.x) * 4;
  const float4 v = *(const float4*)(in + idx);
  ushort4 o;
  o.x = f2bf(v.x); o.y = f2bf(v.y); o.z = f2bf(v.z); o.w = f2bf(v.w);
  *(ushort4*)(out + idx) = o;
}

// ------------------------------------------- transpose+cast: [Kd][Nd] f32 -> [Nd][Kd] bf16
__global__ void transpose_cast(const float* __restrict__ in, u16* __restrict__ out,
                               int Kd, int Nd) {
  __shared__ float t[64][65];
  const int tid = threadIdx.x;
  const int nb = blockIdx.x * 64, kb = blockIdx.y * 64;
#pragma unroll
  for (int it = 0; it < 4; it++) {
    const int flat = it * 1024 + tid * 4;
    const int rr = flat >> 6, cc = flat & 63;
    const float4 v = *(const float4*)(in + (size_t)(kb + rr) * Nd + nb + cc);
    t[rr][cc] = v.x; t[rr][cc + 1] = v.y; t[rr][cc + 2] = v.z; t[rr][cc + 3] = v.w;
  }
  __syncthreads();
#pragma unroll
  for (int it = 0; it < 4; it++) {
    const int flat = it * 1024 + tid * 4;
    const int rn = flat >> 6, ck = flat & 63;
    ushort4 o;
    o.x = f2bf(t[ck][rn]);     o.y = f2bf(t[ck + 1][rn]);
    o.z = f2bf(t[ck + 2][rn]); o.w = f2bf(t[ck + 3][rn]);
    *(ushort4*)(out + (size_t)(nb + rn) * Kd + kb + ck) = o;
  }
}

// ---------------------------------------------------------------- 128x128 bf16 GEMM
// C = A[M][1024] * Bt[N][1024]^T.  EPI=0: scatter qkv (bf16). EPI=1: fp32 C out.
template <int EPI>
__global__ __launch_bounds__(256, 2)
void gemm128(const u16* __restrict__ A, const u16* __restrict__ Bt,
             float* __restrict__ Cout, int Ndim,
             u16* __restrict__ qp, u16* __restrict__ kp, u16* __restrict__ vp) {
  __shared__ alignas(16) u16 As[128 * 32];
  __shared__ alignas(16) u16 Bs[128 * 32];
  const int tid = threadIdx.x;
  const int wave = tid >> 6, lane = tid & 63;
  const int r = lane & 15, qq = lane >> 4;
  const int wm = (wave >> 1) * 64, wn = (wave & 1) * 64;
  const int tn = blockIdx.x * 128, tm = blockIdx.y * 128;

  f32x4 acc[4][4];
#pragma unroll
  for (int i = 0; i < 4; i++)
#pragma unroll
    for (int j = 0; j < 4; j++) acc[i][j] = (f32x4){0.f, 0.f, 0.f, 0.f};

  const int c0 = tid, c1 = tid + 256;  // 16B chunks: row = c>>2, kchunk = c&3
  const u16* ga0 = A + (size_t)(tm + (c0 >> 2)) * 1024 + (c0 & 3) * 8;
  const u16* ga1 = A + (size_t)(tm + (c1 >> 2)) * 1024 + (c1 & 3) * 8;
  const u16* gb0 = Bt + (size_t)(tn + (c0 >> 2)) * 1024 + (c0 & 3) * 8;
  const u16* gb1 = Bt + (size_t)(tn + (c1 >> 2)) * 1024 + (c1 & 3) * 8;
  u16* la0 = As + c0 * 8; u16* la1 = As + c1 * 8;
  u16* lb0 = Bs + c0 * 8; u16* lb1 = Bs + c1 * 8;

  for (int k0 = 0; k0 < 1024; k0 += 32) {
    LDS16(ga0 + k0, la0);
    LDS16(ga1 + k0, la1);
    LDS16(gb0 + k0, lb0);
    LDS16(gb1 + k0, lb1);
    __syncthreads();
    s16x8 af[4], bfr[4];
#pragma unroll
    for (int f = 0; f < 4; f++)
      af[f] = *(const s16x8*)(As + (wm + f * 16 + r) * 32 + qq * 8);
#pragma unroll
    for (int f = 0; f < 4; f++)
      bfr[f] = *(const s16x8*)(Bs + (wn + f * 16 + r) * 32 + qq * 8);
#pragma unroll
    for (int fm = 0; fm < 4; fm++)
#pragma unroll
      for (int fn = 0; fn < 4; fn++)
        acc[fm][fn] = MFMA(af[fm], bfr[fn], acc[fm][fn]);
    __syncthreads();
  }

  // epilogue: C/D layout col = lane&15, row = (lane>>4)*4 + j2
  if (EPI == 0) {
#pragma unroll
    for (int fm = 0; fm < 4; fm++) {
#pragma unroll
      for (int j2 = 0; j2 < 4; j2++) {
        const int mm = tm + wm + fm * 16 + qq * 4 + j2;
        const int bb = mm >> 11, tt = mm & 2047;
#pragma unroll
        for (int fn = 0; fn < 4; fn++) {
          const int n = tn + wn + fn * 16 + r;
          const u16 bv = f2bf(acc[fm][fn][j2]);
          const int which = n >> 10;
          const int hh = (n >> 6) & 15, dd = n & 63;
          const int bhh = bb * 16 + hh;
          if (which == 0)      qp[((size_t)bhh * 2048 + tt) * 64 + dd] = bv;
          else if (which == 1) kp[((size_t)bhh * 2048 + tt) * 64 + dd] = bv;
          else                 vp[((size_t)bhh * 64 + dd) * 2048 + tt] = bv;  // V transposed
        }
      }
    }
  } else {
#pragma unroll
    for (int fm = 0; fm < 4; fm++) {
#pragma unroll
      for (int j2 = 0; j2 < 4; j2++) {
        const int mm = tm + wm + fm * 16 + qq * 4 + j2;
#pragma unroll
        for (int fn = 0; fn < 4; fn++) {
          const int n = tn + wn + fn * 16 + r;
          Cout[(size_t)mm * Ndim + n] = acc[fm][fn][j2];
        }
      }
    }
  }
}

// ---------------------------------------------------------------- flash attention
// 4 waves x 32 q-rows (q-block 128). KVBLK=64, double-buffered swizzled LDS.
// Swapped QK^T: S^T = mfma(K, Q); swapped PV: y^T = mfma(V^T, P^T).
// All softmax stats lane-local for q = lane&31 (lanes l, l^32 hold complementary keys).
__global__ __launch_bounds__(256, 2)
void attn_fwd(const u16* __restrict__ qg, const u16* __restrict__ kg,
              const u16* __restrict__ vtg, u16* __restrict__ yg) {
  __shared__ alignas(16) u16 Kl[2][64 * 64];
  __shared__ alignas(16) u16 Vl[2][64 * 64];
  const int tid = threadIdx.x;
  const int w = tid >> 6, lane = tid & 63;
  const int q5 = lane & 31, hi = lane >> 5;
  const int qb = blockIdx.x * 128;
  const int bh = blockIdx.y;                 // b*16 + h
  const int qrow = qb + w * 32 + q5;
  const float C = 0.18033688011112042f;      // 0.125 * log2(e)

  // Q fragment (B operand of QK^T): lane holds Q[qrow][d], d = ks*16 + hi*8 + j
  const u16* qbase = qg + ((size_t)bh * 2048 + qrow) * 64;
  s16x8 qf[4];
#pragma unroll
  for (int ks = 0; ks < 4; ks++)
    qf[ks] = *(const s16x8*)(qbase + ks * 16 + hi * 8);

  // staging sources: chunk c -> row c>>3, LDS slot c&7 holds global chunk (c&7)^(row&7)
  const int c0 = tid, c1 = tid + 256;
  const int r0 = c0 >> 3, s0 = (c0 & 7) ^ (r0 & 7);
  const int r1 = c1 >> 3, s1 = (c1 & 7) ^ (r1 & 7);
  const u16* kga = kg + ((size_t)bh * 2048 + r0) * 64 + s0 * 8;
  const u16* kgb = kg + ((size_t)bh * 2048 + r1) * 64 + s1 * 8;
  const u16* vga = vtg + ((size_t)bh * 64 + r0) * 2048 + s0 * 8;
  const u16* vgb = vtg + ((size_t)bh * 64 + r1) * 2048 + s1 * 8;

  f32x16 ya, yb;
#pragma unroll
  for (int r = 0; r < 16; r++) { ya[r] = 0.f; yb[r] = 0.f; }
  float m_run = -3.0e38f, l_run = 0.f;

  const int nt = qb / 64 + 2;

#define STAGE(b, t)                                               \
  do {                                                            \
    LDS16(kga + (size_t)(t) * 4096, Kl[b] + c0 * 8);              \
    LDS16(kgb + (size_t)(t) * 4096, Kl[b] + c1 * 8);              \
    LDS16(vga + (size_t)(t) * 64,   Vl[b] + c0 * 8);              \
    LDS16(vgb + (size_t)(t) * 64,   Vl[b] + c1 * 8);              \
  } while (0)

  STAGE(0, 0);
  __syncthreads();

  for (int t = 0; t < nt; t++) {
    const int buf = t & 1;
    if (t + 1 < nt) STAGE(buf ^ 1, t + 1);
    const int kv0 = t * 64;
    const u16* Kb = Kl[buf];
    const u16* Vb = Vl[buf];

    if (kv0 <= qb + w * 32 + 31) {  // wave has live rows in this kv-tile
      // ---- QK^T (swapped): S^T[key][q], key subtiles kb0 = keys 0..31, kb1 = 32..63
      f32x16 sa, sb;
#pragma unroll
      for (int r = 0; r < 16; r++) { sa[r] = 0.f; sb[r] = 0.f; }
#pragma unroll
      for (int ks = 0; ks < 4; ks++) {
        const int slot = ((ks * 2 + hi) ^ (lane & 7)) * 8;
        const s16x8 ka  = *(const s16x8*)(Kb + q5 * 64 + slot);
        const s16x8 kb2 = *(const s16x8*)(Kb + (32 + q5) * 64 + slot);
        sa = MFMA32(ka, qf[ks], sa);
        sb = MFMA32(kb2, qf[ks], sb);
      }

      // ---- causal mask (only diagonal tiles need it)
      if (kv0 + 63 > qb + w * 32) {
#pragma unroll
        for (int r = 0; r < 16; r++) {
          const int kl = kv0 + (r & 3) + 8 * (r >> 2) + 4 * hi;
          if (kl > qrow)      sa[r] = -3.0e38f;
          if (kl + 32 > qrow) sb[r] = -3.0e38f;
        }
      }

      // ---- online softmax (stats lane-local; merge lane pair l <-> l^32)
      float mx = -3.0e38f;
#pragma unroll
      for (int r = 0; r < 16; r++) mx = fmaxf(mx, fmaxf(sa[r], sb[r]));
      mx = fmaxf(mx, __shfl_xor(mx, 32));
      const float m2 = fmaxf(m_run, mx * C);
      const float alpha = EXP2F(m_run - m2);
      m_run = m2;
      const float nm2 = -m2;
      float ls = 0.f;
#pragma unroll
      for (int r = 0; r < 16; r++) {
        const float p0 = EXP2F(fmaf(sa[r], C, nm2));
        const float p1 = EXP2F(fmaf(sb[r], C, nm2));
        sa[r] = p0; sb[r] = p1;
        ls += p0 + p1;
      }
      ls += __shfl_xor(ls, 32);
      l_run = l_run * alpha + ls;
#pragma unroll
      for (int r = 0; r < 16; r++) { ya[r] *= alpha; yb[r] *= alpha; }

      // ---- P -> bf16 B-fragments (P^T as MFMA B operand), per 32-key subtile
      s16x8 bfrag[4];
#pragma unroll
      for (int kb = 0; kb < 2; kb++) {
        const f32x16* pv = kb ? &sb : &sa;
        int wv[8], xv[8];
#pragma unroll
        for (int i = 0; i < 8; i++) wv[i] = cvtpk((*pv)[2 * i], (*pv)[2 * i + 1]);
#pragma unroll
        for (int i = 0; i < 8; i++) xv[i] = __shfl_xor(wv[i], 32);
        union { int4 i4; s16x8 s8; } u0, u1;
        u0.i4 = hi ? make_int4(xv[2], xv[3], wv[2], wv[3])
                   : make_int4(wv[0], wv[1], xv[0], xv[1]);
        u1.i4 = hi ? make_int4(xv[6], xv[7], wv[6], wv[7])
                   : make_int4(wv[4], wv[5], xv[4], xv[5]);
        bfrag[kb * 2]     = u0.s8;
        bfrag[kb * 2 + 1] = u1.s8;
      }

      // ---- PV (swapped): y^T[d][q] += V^T[d][k] * P^T[k][q]
#pragma unroll
      for (int ks4 = 0; ks4 < 4; ks4++) {
        const int sv = ((ks4 * 2 + hi) ^ (lane & 7)) * 8;
        const s16x8 va  = *(const s16x8*)(Vb + q5 * 64 + sv);
        const s16x8 vb2 = *(const s16x8*)(Vb + (32 + q5) * 64 + sv);
        ya = MFMA32(va, bfrag[ks4], ya);
        yb = MFMA32(vb2, bfrag[ks4], yb);
      }
    }
    __syncthreads();
  }
#undef STAGE

  // ---- finalize: y[b][t][h*64+d] = y^T[d][q] / l  (all lane-local)
  const float linv = RCPF(l_run);
  const int b = bh >> 4, h = bh & 15;
  u16* yrow = yg + ((size_t)b * 2048 + qrow) * 1024 + h * 64;
#pragma unroll
  for (int dt = 0; dt < 2; dt++) {
    const f32x16* Y = dt ? &yb : &ya;
#pragma unroll
    for (int p2 = 0; p2 < 8; p2++) {
      const int pk = cvtpk((*Y)[2 * p2] * linv, (*Y)[2 * p2 + 1] * linv);
      const int d0 = dt * 32 + (p2 >> 1) * 8 + hi * 4 + (p2 & 1) * 2;
      *reinterpret_cast<int*>(yrow + d0) = pk;
    }
  }
}

// ---------------------------------------------------------------- launcher
extern "C" void kernel_launch(void* const* d_in, const int* in_sizes, int n_in,
                              void* d_out, int out_size, void* d_ws, size_t ws_size,
                              hipStream_t stream) {
  const float* x = (const float*)d_in[0];       // [4,2048,1024]
  const float* wqkv = (const float*)d_in[1];    // [1024,3072]
  const float* wproj = (const float*)d_in[2];   // [1024,1024]
  float* out = (float*)d_out;                   // [4,2048,1024] fp32

  char* ws = (char*)d_ws;
  u16* xb     = (u16*)(ws);                 // 16.78 MB  [8192][1024] bf16
  u16* wqkvT  = (u16*)(ws + 16777216);      //  6.29 MB  [3072][1024] bf16
  u16* wprojT = (u16*)(ws + 23068672);      //  2.10 MB  [1024][1024] bf16
  u16* qw     = (u16*)(ws + 25165824);      // 16.78 MB  [64][2048][64]
  u16* kw     = (u16*)(ws + 41943040);      // 16.78 MB  [64][2048][64]
  u16* vtw    = (u16*)(ws + 58720256);      // 16.78 MB  [64][64][2048]
  u16* yw     = (u16*)(ws + 75497472);      // 16.78 MB  [8192][1024]
  (void)in_sizes; (void)n_in; (void)out_size; (void)ws_size;

  cast_x_kernel<<<8192, 256, 0, stream>>>(x, xb);
  transpose_cast<<<dim3(48, 16), 256, 0, stream>>>(wqkv, wqkvT, 1024, 3072);
  transpose_cast<<<dim3(16, 16), 256, 0, stream>>>(wproj, wprojT, 1024, 1024);
  gemm128<0><<<dim3(24, 64), 256, 0, stream>>>(xb, wqkvT, nullptr, 3072, qw, kw, vtw);
  attn_fwd<<<dim3(16, 64), 256, 0, stream>>>(qw, kw, vtw, yw);
  gemm128<1><<<dim3(8, 64), 256, 0, stream>>>(yw, wprojT, out, 1024,
                                              nullptr, nullptr, nullptr);
}

// Round 5
// 269.823 us; speedup vs baseline: 1.4573x; 1.1758x over previous
//
#include <hip/hip_runtime.h>

typedef unsigned short u16;
typedef __attribute__((ext_vector_type(8))) short s16x8;   // 8 bf16 (4 VGPRs)
typedef __attribute__((ext_vector_type(4))) float f32x4;   // MFMA 16x16 accumulator
typedef __attribute__((ext_vector_type(16))) float f32x16; // MFMA 32x32 accumulator

#define MFMA(a, b, c) __builtin_amdgcn_mfma_f32_16x16x32_bf16((a), (b), (c), 0, 0, 0)
#define MFMA32(a, b, c) __builtin_amdgcn_mfma_f32_32x32x16_bf16((a), (b), (c), 0, 0, 0)

// async global->LDS, 16B per lane; LDS dest must be wave-uniform base + lane*16
#define LDS16(gp, lp)                                                          \
  __builtin_amdgcn_global_load_lds(                                            \
      (__attribute__((address_space(1))) void*)(gp),                           \
      (__attribute__((address_space(3))) void*)(lp), 16, 0, 0)

#if __has_builtin(__builtin_amdgcn_exp2f)
#define EXP2F(x) __builtin_amdgcn_exp2f(x)
#else
#define EXP2F(x) exp2f(x)
#endif
#if __has_builtin(__builtin_amdgcn_rcpf)
#define RCPF(x) __builtin_amdgcn_rcpf(x)
#else
#define RCPF(x) (1.0f / (x))
#endif

__device__ __forceinline__ u16 f2bf(float f) {
  unsigned u = __float_as_uint(f);
  u += 0x7fffu + ((u >> 16) & 1u);   // round-to-nearest-even
  return (u16)(u >> 16);
}

// pack two f32 -> 2x bf16 in one VGPR (lo = a, hi = b), RNE
__device__ __forceinline__ int cvtpk(float a, float b) {
  int r;
  asm("v_cvt_pk_bf16_f32 %0, %1, %2" : "=v"(r) : "v"(a), "v"(b));
  return r;
}

// ---------------------------------------------------------------- cast x -> bf16
__global__ void cast_x_kernel(const float* __restrict__ in, u16* __restrict__ out) {
  const int idx = (blockIdx.x * 256 + threadIdx.x) * 4;
  const float4 v = *(const float4*)(in + idx);
  ushort4 o;
  o.x = f2bf(v.x); o.y = f2bf(v.y); o.z = f2bf(v.z); o.w = f2bf(v.w);
  *(ushort4*)(out + idx) = o;
}

// ------------------------------------------- transpose+cast: [Kd][Nd] f32 -> [Nd][Kd] bf16
__global__ void transpose_cast(const float* __restrict__ in, u16* __restrict__ out,
                               int Kd, int Nd) {
  __shared__ float t[64][65];
  const int tid = threadIdx.x;
  const int nb = blockIdx.x * 64, kb = blockIdx.y * 64;
#pragma unroll
  for (int it = 0; it < 4; it++) {
    const int flat = it * 1024 + tid * 4;
    const int rr = flat >> 6, cc = flat & 63;
    const float4 v = *(const float4*)(in + (size_t)(kb + rr) * Nd + nb + cc);
    t[rr][cc] = v.x; t[rr][cc + 1] = v.y; t[rr][cc + 2] = v.z; t[rr][cc + 3] = v.w;
  }
  __syncthreads();
#pragma unroll
  for (int it = 0; it < 4; it++) {
    const int flat = it * 1024 + tid * 4;
    const int rn = flat >> 6, ck = flat & 63;
    ushort4 o;
    o.x = f2bf(t[ck][rn]);     o.y = f2bf(t[ck + 1][rn]);
    o.z = f2bf(t[ck + 2][rn]); o.w = f2bf(t[ck + 3][rn]);
    *(ushort4*)(out + (size_t)(nb + rn) * Kd + kb + ck) = o;
  }
}

// ---------------------------------------------------------------- 128x128 bf16 GEMM
// C = A[M][1024] * Bt[N][1024]^T.  EPI=0: scatter qkv (bf16). EPI=1: fp32 C out.
// Block mapping: bijective XCD swizzle of the flat block id (grid %8 == 0).
template <int EPI>
__global__ __launch_bounds__(256, 2)
void gemm128(const u16* __restrict__ A, const u16* __restrict__ Bt,
             float* __restrict__ Cout, int Ndim,
             u16* __restrict__ qp, u16* __restrict__ kp, u16* __restrict__ vp) {
  __shared__ alignas(16) u16 As[128 * 32];
  __shared__ alignas(16) u16 Bs[128 * 32];
  const int tid = threadIdx.x;
  const int wave = tid >> 6, lane = tid & 63;
  const int r = lane & 15, qq = lane >> 4;
  const int wm = (wave >> 1) * 64, wn = (wave & 1) * 64;
  const int gx = gridDim.x;
  const int nwg = gx * gridDim.y;
  const int bid = blockIdx.x + gx * blockIdx.y;
  const int swz = (bid & 7) * (nwg >> 3) + (bid >> 3);   // XCD-contiguous chunks
  const int tn = (swz % gx) * 128, tm = (swz / gx) * 128;

  f32x4 acc[4][4];
#pragma unroll
  for (int i = 0; i < 4; i++)
#pragma unroll
    for (int j = 0; j < 4; j++) acc[i][j] = (f32x4){0.f, 0.f, 0.f, 0.f};

  const int c0 = tid, c1 = tid + 256;  // 16B chunks: row = c>>2, kchunk = c&3
  const u16* ga0 = A + (size_t)(tm + (c0 >> 2)) * 1024 + (c0 & 3) * 8;
  const u16* ga1 = A + (size_t)(tm + (c1 >> 2)) * 1024 + (c1 & 3) * 8;
  const u16* gb0 = Bt + (size_t)(tn + (c0 >> 2)) * 1024 + (c0 & 3) * 8;
  const u16* gb1 = Bt + (size_t)(tn + (c1 >> 2)) * 1024 + (c1 & 3) * 8;
  u16* la0 = As + c0 * 8; u16* la1 = As + c1 * 8;
  u16* lb0 = Bs + c0 * 8; u16* lb1 = Bs + c1 * 8;

  for (int k0 = 0; k0 < 1024; k0 += 32) {
    LDS16(ga0 + k0, la0);
    LDS16(ga1 + k0, la1);
    LDS16(gb0 + k0, lb0);
    LDS16(gb1 + k0, lb1);
    __syncthreads();
    s16x8 af[4], bfr[4];
#pragma unroll
    for (int f = 0; f < 4; f++)
      af[f] = *(const s16x8*)(As + (wm + f * 16 + r) * 32 + qq * 8);
#pragma unroll
    for (int f = 0; f < 4; f++)
      bfr[f] = *(const s16x8*)(Bs + (wn + f * 16 + r) * 32 + qq * 8);
    __builtin_amdgcn_s_setprio(1);
#pragma unroll
    for (int fm = 0; fm < 4; fm++)
#pragma unroll
      for (int fn = 0; fn < 4; fn++)
        acc[fm][fn] = MFMA(af[fm], bfr[fn], acc[fm][fn]);
    __builtin_amdgcn_s_setprio(0);
    __syncthreads();
  }

  // epilogue: C/D layout col = lane&15, row = (lane>>4)*4 + j2
  if (EPI == 0) {
#pragma unroll
    for (int fm = 0; fm < 4; fm++) {
#pragma unroll
      for (int j2 = 0; j2 < 4; j2++) {
        const int mm = tm + wm + fm * 16 + qq * 4 + j2;
        const int bb = mm >> 11, tt = mm & 2047;
#pragma unroll
        for (int fn = 0; fn < 4; fn++) {
          const int n = tn + wn + fn * 16 + r;
          const u16 bv = f2bf(acc[fm][fn][j2]);
          const int which = n >> 10;
          const int hh = (n >> 6) & 15, dd = n & 63;
          const int bhh = bb * 16 + hh;
          if (which == 0)      qp[((size_t)bhh * 2048 + tt) * 64 + dd] = bv;
          else if (which == 1) kp[((size_t)bhh * 2048 + tt) * 64 + dd] = bv;
          else                 vp[((size_t)bhh * 64 + dd) * 2048 + tt] = bv;  // V transposed
        }
      }
    }
  } else {
#pragma unroll
    for (int fm = 0; fm < 4; fm++) {
#pragma unroll
      for (int j2 = 0; j2 < 4; j2++) {
        const int mm = tm + wm + fm * 16 + qq * 4 + j2;
#pragma unroll
        for (int fn = 0; fn < 4; fn++) {
          const int n = tn + wn + fn * 16 + r;
          Cout[(size_t)mm * Ndim + n] = acc[fm][fn][j2];
        }
      }
    }
  }
}

// ---------------------------------------------------------------- flash attention
// 4 waves x 32 q-rows (q-block 128). KVBLK=64, double-buffered swizzled LDS.
// Swapped QK^T: S^T = mfma(K, Q); swapped PV: y^T = mfma(V^T, P^T).
// Grid: x = bh (uniform work), y = q-tile, heavy tiles first (LPT scheduling).
__global__ __launch_bounds__(256, 2)
void attn_fwd(const u16* __restrict__ qg, const u16* __restrict__ kg,
              const u16* __restrict__ vtg, u16* __restrict__ yg) {
  __shared__ alignas(16) u16 Kl[2][64 * 64];
  __shared__ alignas(16) u16 Vl[2][64 * 64];
  const int tid = threadIdx.x;
  const int w = tid >> 6, lane = tid & 63;
  const int q5 = lane & 31, hi = lane >> 5;
  const int bh = blockIdx.x;                               // b*16 + h (uniform)
  const int qi = (int)(gridDim.y - 1 - blockIdx.y);        // heavy-first
  const int qb = qi * 128;
  const int qrow = qb + w * 32 + q5;
  const float C = 0.18033688011112042f;      // 0.125 * log2(e)

  // Q fragment (B operand of QK^T): lane holds Q[qrow][d], d = ks*16 + hi*8 + j
  const u16* qbase = qg + ((size_t)bh * 2048 + qrow) * 64;
  s16x8 qf[4];
#pragma unroll
  for (int ks = 0; ks < 4; ks++)
    qf[ks] = *(const s16x8*)(qbase + ks * 16 + hi * 8);

  // staging sources: chunk c -> row c>>3, LDS slot c&7 holds global chunk (c&7)^(row&7)
  const int c0 = tid, c1 = tid + 256;
  const int r0 = c0 >> 3, s0 = (c0 & 7) ^ (r0 & 7);
  const int r1 = c1 >> 3, s1 = (c1 & 7) ^ (r1 & 7);
  const u16* kga = kg + ((size_t)bh * 2048 + r0) * 64 + s0 * 8;
  const u16* kgb = kg + ((size_t)bh * 2048 + r1) * 64 + s1 * 8;
  const u16* vga = vtg + ((size_t)bh * 64 + r0) * 2048 + s0 * 8;
  const u16* vgb = vtg + ((size_t)bh * 64 + r1) * 2048 + s1 * 8;

  f32x16 ya, yb;
#pragma unroll
  for (int r = 0; r < 16; r++) { ya[r] = 0.f; yb[r] = 0.f; }
  float m_run = -3.0e38f, l_run = 0.f;

  const int nt = qb / 64 + 2;

#define STAGE(b, t)                                               \
  do {                                                            \
    LDS16(kga + (size_t)(t) * 4096, Kl[b] + c0 * 8);              \
    LDS16(kgb + (size_t)(t) * 4096, Kl[b] + c1 * 8);              \
    LDS16(vga + (size_t)(t) * 64,   Vl[b] + c0 * 8);              \
    LDS16(vgb + (size_t)(t) * 64,   Vl[b] + c1 * 8);              \
  } while (0)

  STAGE(0, 0);
  __syncthreads();

  for (int t = 0; t < nt; t++) {
    const int buf = t & 1;
    if (t + 1 < nt) STAGE(buf ^ 1, t + 1);
    const int kv0 = t * 64;
    const u16* Kb = Kl[buf];
    const u16* Vb = Vl[buf];

    if (kv0 <= qb + w * 32 + 31) {  // wave has live rows in this kv-tile
      // ---- QK^T (swapped): S^T[key][q], key subtiles kb0 = keys 0..31, kb1 = 32..63
      f32x16 sa, sb;
#pragma unroll
      for (int r = 0; r < 16; r++) { sa[r] = 0.f; sb[r] = 0.f; }
      __builtin_amdgcn_s_setprio(1);
#pragma unroll
      for (int ks = 0; ks < 4; ks++) {
        const int slot = ((ks * 2 + hi) ^ (lane & 7)) * 8;
        const s16x8 ka  = *(const s16x8*)(Kb + q5 * 64 + slot);
        const s16x8 kb2 = *(const s16x8*)(Kb + (32 + q5) * 64 + slot);
        sa = MFMA32(ka, qf[ks], sa);
        sb = MFMA32(kb2, qf[ks], sb);
      }
      __builtin_amdgcn_s_setprio(0);

      // ---- hoist V-fragment LDS reads: latency hides under softmax VALU
      s16x8 va[4], vb2[4];
#pragma unroll
      for (int ks4 = 0; ks4 < 4; ks4++) {
        const int sv = ((ks4 * 2 + hi) ^ (lane & 7)) * 8;
        va[ks4]  = *(const s16x8*)(Vb + q5 * 64 + sv);
        vb2[ks4] = *(const s16x8*)(Vb + (32 + q5) * 64 + sv);
      }

      // ---- causal mask (only diagonal tiles need it)
      if (kv0 + 63 > qb + w * 32) {
#pragma unroll
        for (int r = 0; r < 16; r++) {
          const int kl = kv0 + (r & 3) + 8 * (r >> 2) + 4 * hi;
          if (kl > qrow)      sa[r] = -3.0e38f;
          if (kl + 32 > qrow) sb[r] = -3.0e38f;
        }
      }

      // ---- online softmax (stats lane-local; merge lane pair l <-> l^32)
      float mx0 = -3.0e38f, mx1 = -3.0e38f, mx2 = -3.0e38f, mx3 = -3.0e38f;
#pragma unroll
      for (int r = 0; r < 16; r += 4) {
        mx0 = fmaxf(mx0, fmaxf(sa[r], sb[r]));
        mx1 = fmaxf(mx1, fmaxf(sa[r + 1], sb[r + 1]));
        mx2 = fmaxf(mx2, fmaxf(sa[r + 2], sb[r + 2]));
        mx3 = fmaxf(mx3, fmaxf(sa[r + 3], sb[r + 3]));
      }
      float mx = fmaxf(fmaxf(mx0, mx1), fmaxf(mx2, mx3));
      mx = fmaxf(mx, __shfl_xor(mx, 32));
      const float mxs = mx * C;

      // defer-max (T13): skip O-rescale while per-tile max growth <= 8 (P <= 2^8)
      if (!__all(mxs - m_run <= 8.0f)) {
        const float m2 = fmaxf(m_run, mxs);
        const float alpha = EXP2F(m_run - m2);
        m_run = m2;
        l_run *= alpha;
#pragma unroll
        for (int r = 0; r < 16; r++) { ya[r] *= alpha; yb[r] *= alpha; }
      }

      const float nm2 = -m_run;
      float ls0 = 0.f, ls1 = 0.f, ls2 = 0.f, ls3 = 0.f;
#pragma unroll
      for (int r = 0; r < 16; r += 4) {
        float p;
        p = EXP2F(fmaf(sa[r], C, nm2));     sa[r] = p;     ls0 += p;
        p = EXP2F(fmaf(sa[r + 1], C, nm2)); sa[r + 1] = p; ls1 += p;
        p = EXP2F(fmaf(sa[r + 2], C, nm2)); sa[r + 2] = p; ls2 += p;
        p = EXP2F(fmaf(sa[r + 3], C, nm2)); sa[r + 3] = p; ls3 += p;
        p = EXP2F(fmaf(sb[r], C, nm2));     sb[r] = p;     ls0 += p;
        p = EXP2F(fmaf(sb[r + 1], C, nm2)); sb[r + 1] = p; ls1 += p;
        p = EXP2F(fmaf(sb[r + 2], C, nm2)); sb[r + 2] = p; ls2 += p;
        p = EXP2F(fmaf(sb[r + 3], C, nm2)); sb[r + 3] = p; ls3 += p;
      }
      float ls = (ls0 + ls1) + (ls2 + ls3);
      ls += __shfl_xor(ls, 32);
      l_run += ls;

      // ---- P -> bf16 B-fragments (P^T as MFMA B operand), per 32-key subtile
      s16x8 bfrag[4];
#pragma unroll
      for (int kb = 0; kb < 2; kb++) {
        const f32x16* pv = kb ? &sb : &sa;
        int wv[8], xv[8];
#pragma unroll
        for (int i = 0; i < 8; i++) wv[i] = cvtpk((*pv)[2 * i], (*pv)[2 * i + 1]);
#pragma unroll
        for (int i = 0; i < 8; i++) xv[i] = __shfl_xor(wv[i], 32);
        union { int4 i4; s16x8 s8; } u0, u1;
        u0.i4 = hi ? make_int4(xv[2], xv[3], wv[2], wv[3])
                   : make_int4(wv[0], wv[1], xv[0], xv[1]);
        u1.i4 = hi ? make_int4(xv[6], xv[7], wv[6], wv[7])
                   : make_int4(wv[4], wv[5], xv[4], xv[5]);
        bfrag[kb * 2]     = u0.s8;
        bfrag[kb * 2 + 1] = u1.s8;
      }

      // ---- PV (swapped): y^T[d][q] += V^T[d][k] * P^T[k][q]
      __builtin_amdgcn_s_setprio(1);
#pragma unroll
      for (int ks4 = 0; ks4 < 4; ks4++) {
        ya = MFMA32(va[ks4], bfrag[ks4], ya);
        yb = MFMA32(vb2[ks4], bfrag[ks4], yb);
      }
      __builtin_amdgcn_s_setprio(0);
    }
    __syncthreads();
  }
#undef STAGE

  // ---- finalize: y[b][t][h*64+d] = y^T[d][q] / l  (all lane-local)
  const float linv = RCPF(l_run);
  const int b = bh >> 4, h = bh & 15;
  u16* yrow = yg + ((size_t)b * 2048 + qrow) * 1024 + h * 64;
#pragma unroll
  for (int dt = 0; dt < 2; dt++) {
    const f32x16* Y = dt ? &yb : &ya;
#pragma unroll
    for (int p2 = 0; p2 < 8; p2++) {
      const int pk = cvtpk((*Y)[2 * p2] * linv, (*Y)[2 * p2 + 1] * linv);
      const int d0 = dt * 32 + (p2 >> 1) * 8 + hi * 4 + (p2 & 1) * 2;
      *reinterpret_cast<int*>(yrow + d0) = pk;
    }
  }
}

// ---------------------------------------------------------------- launcher
extern "C" void kernel_launch(void* const* d_in, const int* in_sizes, int n_in,
                              void* d_out, int out_size, void* d_ws, size_t ws_size,
                              hipStream_t stream) {
  const float* x = (const float*)d_in[0];       // [4,2048,1024]
  const float* wqkv = (const float*)d_in[1];    // [1024,3072]
  const float* wproj = (const float*)d_in[2];   // [1024,1024]
  float* out = (float*)d_out;                   // [4,2048,1024] fp32

  char* ws = (char*)d_ws;
  u16* xb     = (u16*)(ws);                 // 16.78 MB  [8192][1024] bf16
  u16* wqkvT  = (u16*)(ws + 16777216);      //  6.29 MB  [3072][1024] bf16
  u16* wprojT = (u16*)(ws + 23068672);      //  2.10 MB  [1024][1024] bf16
  u16* qw     = (u16*)(ws + 25165824);      // 16.78 MB  [64][2048][64]
  u16* kw     = (u16*)(ws + 41943040);      // 16.78 MB  [64][2048][64]
  u16* vtw    = (u16*)(ws + 58720256);      // 16.78 MB  [64][64][2048]
  u16* yw     = (u16*)(ws + 75497472);      // 16.78 MB  [8192][1024]
  (void)in_sizes; (void)n_in; (void)out_size; (void)ws_size;

  cast_x_kernel<<<8192, 256, 0, stream>>>(x, xb);
  transpose_cast<<<dim3(48, 16), 256, 0, stream>>>(wqkv, wqkvT, 1024, 3072);
  transpose_cast<<<dim3(16, 16), 256, 0, stream>>>(wproj, wprojT, 1024, 1024);
  gemm128<0><<<dim3(24, 64), 256, 0, stream>>>(xb, wqkvT, nullptr, 3072, qw, kw, vtw);
  attn_fwd<<<dim3(64, 16), 256, 0, stream>>>(qw, kw, vtw, yw);
  gemm128<1><<<dim3(8, 64), 256, 0, stream>>>(yw, wprojT, out, 1024,
                                              nullptr, nullptr, nullptr);
}